// Round 4
// baseline (936.918 us; speedup 1.0000x reference)
//
#include <hip/hip_runtime.h>

typedef __attribute__((ext_vector_type(8)))  __bf16 bf16x8;
typedef __attribute__((ext_vector_type(16))) float  f32x16;

#define NPTS   131072          // B*H*W = 32*64*64
#define KCODES 1024
#define DDIM   64
#define HWSZ   4096

// d_out layout (floats): out[8388608] | loss | perplexity | encodings[131072*1024]
#define LOSS_OFF    8388608
#define PERP_OFF    8388609
#define ENC_OFF     8388610

// d_ws layout (bytes):
//   [0,4096)      e2 f32[1024]
//   [4096,8192)   hist i32[1024]
//   [8192,10240)  blockLoss f32[512]
//   [16384,409600) planes: 3 x 8 slots x 1024 codes x 8 bf16  (exact MFMA A-frag order)
#define PLANES_OFF  16384
#define WS_NEED     (16384 + 3 * 8 * 1024 * 8 * 2)

__device__ __forceinline__ unsigned rnhi(float x) {
    // round-to-nearest-even bf16, returned as fp32 bit pattern (low 16 bits zero)
    unsigned u = __float_as_uint(x);
    return (u + 0x7fffu + ((u >> 16) & 1u)) & 0xffff0000u;
}

__device__ __forceinline__ void split3(float x, unsigned short& h1, unsigned short& h2, unsigned short& h3) {
    unsigned a = rnhi(x); float r1 = x - __uint_as_float(a);
    unsigned b = rnhi(r1); float r2 = r1 - __uint_as_float(b);
    unsigned c = rnhi(r2);
    h1 = (unsigned short)(a >> 16);
    h2 = (unsigned short)(b >> 16);
    h3 = (unsigned short)(c >> 16);
}

// ---- prep: e2, hist-zero, and the 3-way bf16 split of -2*emb in fragment order ----
__global__ __launch_bounds__(256) void prep_kernel(const float* __restrict__ emb,
                                                   float* __restrict__ e2,
                                                   int* __restrict__ hist,
                                                   unsigned short* __restrict__ planes) {
    int k = blockIdx.x * 256 + threadIdx.x;      // code id, 0..1023
    hist[k] = 0;
    float row[DDIM];
    const float4* r = (const float4*)(emb + (size_t)k * DDIM);
    float s0 = 0.f, s1 = 0.f, s2 = 0.f, s3 = 0.f;
#pragma unroll
    for (int i = 0; i < 16; ++i) {
        float4 v = r[i];
        row[4 * i + 0] = v.x; row[4 * i + 1] = v.y;
        row[4 * i + 2] = v.z; row[4 * i + 3] = v.w;
        s0 = fmaf(v.x, v.x, s0);
        s1 = fmaf(v.y, v.y, s1);
        s2 = fmaf(v.z, v.z, s2);
        s3 = fmaf(v.w, v.w, s3);
    }
    e2[k] = (s0 + s1) + (s2 + s3);
#pragma unroll
    for (int sl = 0; sl < 8; ++sl) {
        unsigned w1[4], w2[4], w3[4];
#pragma unroll
        for (int m = 0; m < 4; ++m) {
            unsigned short a0, b0, c0, a1, b1, c1;
            split3(-2.f * row[sl * 8 + 2 * m    ], a0, b0, c0);
            split3(-2.f * row[sl * 8 + 2 * m + 1], a1, b1, c1);
            w1[m] = (unsigned)a0 | ((unsigned)a1 << 16);
            w2[m] = (unsigned)b0 | ((unsigned)b1 << 16);
            w3[m] = (unsigned)c0 | ((unsigned)c1 << 16);
        }
        const size_t off = ((size_t)sl * 1024 + k) * 8;
        *(uint4*)&planes[0 * 65536 + off] = make_uint4(w1[0], w1[1], w1[2], w1[3]);
        *(uint4*)&planes[1 * 65536 + off] = make_uint4(w2[0], w2[1], w2[2], w2[3]);
        *(uint4*)&planes[2 * 65536 + off] = make_uint4(w3[0], w3[1], w3[2], w3[3]);
    }
}

// ---- main kernel: A-frags straight from global (L2-hot), no loop barriers ----
__global__ __launch_bounds__(512, 4) void vq_mfma2(
    const float* __restrict__ z_e, const bf16x8* __restrict__ planes,
    const float* __restrict__ e2g, const float* __restrict__ emb,
    float* __restrict__ out, float* __restrict__ enc,
    int* __restrict__ hist, float* __restrict__ blockLoss)
{
    __shared__ float se2[KCODES];
    __shared__ int   sidx[256];
    __shared__ float swsum[8];

    const int tid  = threadIdx.x, bid = blockIdx.x;
    const int lane = tid & 63,    wid = tid >> 6;
    const int hi   = lane >> 5,   col = lane & 31;

    for (int i = tid; i < KCODES; i += 512) se2[i] = e2g[i];

    float* encSlice = enc + (size_t)bid * 256 * KCODES;
    float4* encF4   = (float4*)(encSlice + 2);          // 16B-aligned interior

    // ---- build B fragments: this wave's 32 points, 3-way bf16 split of z ----
    const int n  = bid * 256 + wid * 32 + col;
    const int b  = n >> 12, hw = n & (HWSZ - 1);
    const float* zp = z_e + (size_t)b * (DDIM * HWSZ) + hw;

    bf16x8 Bv[3][4];
    float zzp = 0.f;
#pragma unroll
    for (int kk = 0; kk < 4; ++kk) {
        union { unsigned u[4]; bf16x8 v; } p1, p2, p3;
#pragma unroll
        for (int m = 0; m < 4; ++m) {
            float x0 = zp[(size_t)(16 * kk + 8 * hi + 2 * m    ) * HWSZ];
            float x1 = zp[(size_t)(16 * kk + 8 * hi + 2 * m + 1) * HWSZ];
            zzp = fmaf(x0, x0, zzp);
            zzp = fmaf(x1, x1, zzp);
            unsigned short a0, b0, c0, a1, b1, c1;
            split3(x0, a0, b0, c0);
            split3(x1, a1, b1, c1);
            p1.u[m] = (unsigned)a0 | ((unsigned)a1 << 16);
            p2.u[m] = (unsigned)b0 | ((unsigned)b1 << 16);
            p3.u[m] = (unsigned)c0 | ((unsigned)c1 << 16);
        }
        Bv[0][kk] = p1.v; Bv[1][kk] = p2.v; Bv[2][kk] = p3.v;
    }
    __syncthreads();                                    // se2 ready

    float best = 3.4e38f;
    int   bestk = 0;
    const float4 z4 = make_float4(0.f, 0.f, 0.f, 0.f);

    for (int chunk = 0; chunk < 8; ++chunk) {
        for (int t = 0; t < 4; ++t) {
            f32x16 acc0 = {0.f,0.f,0.f,0.f,0.f,0.f,0.f,0.f,0.f,0.f,0.f,0.f,0.f,0.f,0.f,0.f};
            f32x16 acc1 = {0.f,0.f,0.f,0.f,0.f,0.f,0.f,0.f,0.f,0.f,0.f,0.f,0.f,0.f,0.f,0.f};
            const int code0 = chunk * 128 + 32 * t + col;
#pragma unroll
            for (int kk = 0; kk < 4; ++kk) {
                const bf16x8* ap = planes + (size_t)(2 * kk + hi) * 1024 + code0;
                bf16x8 a1 = ap[0];
                bf16x8 a2 = ap[8192];
                bf16x8 a3 = ap[16384];
                // 8 product terms (drop only (3,3)); two independent acc chains
                acc0 = __builtin_amdgcn_mfma_f32_32x32x16_bf16(a1, Bv[0][kk], acc0, 0, 0, 0);
                acc1 = __builtin_amdgcn_mfma_f32_32x32x16_bf16(a1, Bv[1][kk], acc1, 0, 0, 0);
                acc0 = __builtin_amdgcn_mfma_f32_32x32x16_bf16(a2, Bv[0][kk], acc0, 0, 0, 0);
                acc1 = __builtin_amdgcn_mfma_f32_32x32x16_bf16(a2, Bv[1][kk], acc1, 0, 0, 0);
                acc0 = __builtin_amdgcn_mfma_f32_32x32x16_bf16(a1, Bv[2][kk], acc0, 0, 0, 0);
                acc1 = __builtin_amdgcn_mfma_f32_32x32x16_bf16(a3, Bv[0][kk], acc1, 0, 0, 0);
                acc0 = __builtin_amdgcn_mfma_f32_32x32x16_bf16(a2, Bv[2][kk], acc0, 0, 0, 0);
                acc1 = __builtin_amdgcn_mfma_f32_32x32x16_bf16(a3, Bv[1][kk], acc1, 0, 0, 0);
            }
            // drip-feed enc zero-stores: 4 float4/thread/tile, coalesced,
            // no barrier -> drains in background on the vmem pipe
            {
                const int tile = chunk * 4 + t;
#pragma unroll
                for (int j = 0; j < 4; ++j) {
                    const int idx = tile * 2048 + j * 512 + tid;
                    if (idx != 65535) encF4[idx] = z4;
                }
            }
            const int cbase = chunk * 128 + 32 * t + 4 * hi;
#pragma unroll
            for (int r = 0; r < 16; ++r) {
                const int row  = (r & 3) + 8 * (r >> 2);   // verified C/D map (+4*hi folded into cbase)
                const int code = cbase + row;
                const float sc = (acc0[r] + acc1[r]) + se2[code];
                if (sc < best) { best = sc; bestk = code; }
            }
        }
    }

    // unaligned head/tail of this block's slice (base ≡ 8 mod 16 bytes)
    if (tid == 0) *(float2*)encSlice = make_float2(0.f, 0.f);
    if (tid == 1) *(float2*)(encSlice + 262142) = make_float2(0.f, 0.f);

    // ---- merge lane pairs (col, col+32): other lane covers the other 16 rows ----
    float obest = __shfl_down(best, 32);
    int   oidx  = __shfl_down(bestk, 32);
    float ozz   = __shfl_down(zzp, 32);
    if (obest < best || (obest == best && oidx < bestk)) { best = obest; bestk = oidx; }
    const float zz = zzp + ozz;
    float contrib = (lane < 32) ? (best + zz) : 0.f;
    if (lane < 32) {
        sidx[wid * 32 + col] = bestk;
        atomicAdd(&hist[bestk], 1);
    }
#pragma unroll
    for (int off = 32; off > 0; off >>= 1) contrib += __shfl_down(contrib, off);
    if (lane == 0) swsum[wid] = contrib;
    __syncthreads();   // drains ALL zero-stores (vmcnt 0 before s_barrier) + sidx visible
    if (tid == 0) {
        float s = 0.f;
        for (int i = 0; i < 8; ++i) s += swsum[i];
        blockLoss[bid] = s;
    }

    // ---- scatter the 1.0s (zeros for this slice are complete & visible) ----
    if (lane < 32) {
        const int nn = bid * 256 + wid * 32 + col;
        enc[(size_t)nn * KCODES + bestk] = 1.0f;
    }

    // ---- quantized output: 2 threads/point, coalesced per channel ----
    {
        const int i  = tid & 255, c0 = (tid >> 8) * 32;
        const int k  = sidx[i];
        const int nn = bid * 256 + i, bb = nn >> 12, hh = nn & (HWSZ - 1);
        const float4* er = (const float4*)(emb + (size_t)k * DDIM + c0);
        float* ob = out + (size_t)bb * (DDIM * HWSZ) + hh;
#pragma unroll
        for (int m = 0; m < 8; ++m) {
            float4 q = er[m];
            ob[(size_t)(c0 + 4 * m    ) * HWSZ] = q.x;
            ob[(size_t)(c0 + 4 * m + 1) * HWSZ] = q.y;
            ob[(size_t)(c0 + 4 * m + 2) * HWSZ] = q.z;
            ob[(size_t)(c0 + 4 * m + 3) * HWSZ] = q.w;
        }
    }
}

// =================== fallback path (ws too small): round-3 kernels ===================
__global__ __launch_bounds__(256) void e2_kernel(const float* __restrict__ emb,
                                                 float* __restrict__ e2,
                                                 int* __restrict__ hist) {
    int k = blockIdx.x * 256 + threadIdx.x;
    hist[k] = 0;
    const float4* r = (const float4*)(emb + (size_t)k * DDIM);
    float s0 = 0.f, s1 = 0.f, s2 = 0.f, s3 = 0.f;
#pragma unroll
    for (int i = 0; i < 16; ++i) {
        float4 v = r[i];
        s0 = fmaf(v.x, v.x, s0);
        s1 = fmaf(v.y, v.y, s1);
        s2 = fmaf(v.z, v.z, s2);
        s3 = fmaf(v.w, v.w, s3);
    }
    e2[k] = (s0 + s1) + (s2 + s3);
}

__global__ __launch_bounds__(512, 4) void vq_mfma(
    const float* __restrict__ z_e, const float* __restrict__ emb,
    const float* __restrict__ e2g, float* __restrict__ out,
    float* __restrict__ enc, int* __restrict__ hist,
    float* __restrict__ blockLoss)
{
    __shared__ unsigned short planeA[3 * 8 * 1024];
    __shared__ float se2[KCODES];
    __shared__ int   sidx[256];
    __shared__ float swsum[8];

    const int tid  = threadIdx.x, bid = blockIdx.x;
    const int lane = tid & 63,    wid = tid >> 6;
    const int hi   = lane >> 5,   col = lane & 31;

    for (int i = tid; i < KCODES; i += 512) se2[i] = e2g[i];

    float* encSlice = enc + (size_t)bid * 256 * KCODES;
    float4* encF4   = (float4*)(encSlice + 2);

    const int n  = bid * 256 + wid * 32 + col;
    const int b  = n >> 12, hw = n & (HWSZ - 1);
    const float* zp = z_e + (size_t)b * (DDIM * HWSZ) + hw;

    bf16x8 Bv[3][4];
    float zzp = 0.f;
#pragma unroll
    for (int kk = 0; kk < 4; ++kk) {
        union { unsigned u[4]; bf16x8 v; } p1, p2, p3;
#pragma unroll
        for (int m = 0; m < 4; ++m) {
            float x0 = zp[(size_t)(16 * kk + 8 * hi + 2 * m    ) * HWSZ];
            float x1 = zp[(size_t)(16 * kk + 8 * hi + 2 * m + 1) * HWSZ];
            zzp = fmaf(x0, x0, zzp);
            zzp = fmaf(x1, x1, zzp);
            unsigned short a0, b0, c0, a1, b1, c1;
            split3(x0, a0, b0, c0);
            split3(x1, a1, b1, c1);
            p1.u[m] = (unsigned)a0 | ((unsigned)a1 << 16);
            p2.u[m] = (unsigned)b0 | ((unsigned)b1 << 16);
            p3.u[m] = (unsigned)c0 | ((unsigned)c1 << 16);
        }
        Bv[0][kk] = p1.v; Bv[1][kk] = p2.v; Bv[2][kk] = p3.v;
    }

    float best = 3.4e38f;
    int   bestk = 0;

    for (int chunk = 0; chunk < 8; ++chunk) {
        __syncthreads();
#pragma unroll
        for (int it = 0; it < 2; ++it) {
            const int code = tid & 127;
            const int sl   = (tid >> 7) + 4 * it;
            const float4* ep = (const float4*)(emb + (size_t)(chunk * 128 + code) * DDIM + sl * 8);
            float4 va = ep[0], vb = ep[1];
            float xs[8] = {va.x, va.y, va.z, va.w, vb.x, vb.y, vb.z, vb.w};
            unsigned w1[4], w2[4], w3[4];
#pragma unroll
            for (int m = 0; m < 4; ++m) {
                unsigned short a0, b0, c0, a1, b1, c1;
                split3(-2.f * xs[2 * m    ], a0, b0, c0);
                split3(-2.f * xs[2 * m + 1], a1, b1, c1);
                w1[m] = (unsigned)a0 | ((unsigned)a1 << 16);
                w2[m] = (unsigned)b0 | ((unsigned)b1 << 16);
                w3[m] = (unsigned)c0 | ((unsigned)c1 << 16);
            }
            const int off = sl * 1024 + code * 8;
            *(uint4*)&planeA[0 * 8192 + off] = make_uint4(w1[0], w1[1], w1[2], w1[3]);
            *(uint4*)&planeA[1 * 8192 + off] = make_uint4(w2[0], w2[1], w2[2], w2[3]);
            *(uint4*)&planeA[2 * 8192 + off] = make_uint4(w3[0], w3[1], w3[2], w3[3]);
        }
        __syncthreads();

        {
            const float4 z4 = make_float4(0.f, 0.f, 0.f, 0.f);
            const int base = chunk * 8192 + tid;
#pragma unroll
            for (int it = 0; it < 16; ++it) {
                const int idx = base + it * 512;
                if (idx < 65535) encF4[idx] = z4;
            }
            if (chunk == 0) {
                if (tid == 0) *(float2*)encSlice = make_float2(0.f, 0.f);
                if (tid == 1) *(float2*)(encSlice + 262142) = make_float2(0.f, 0.f);
            }
        }

        for (int t = 0; t < 4; ++t) {
            f32x16 acc0 = {0.f,0.f,0.f,0.f,0.f,0.f,0.f,0.f,0.f,0.f,0.f,0.f,0.f,0.f,0.f,0.f};
            f32x16 acc1 = {0.f,0.f,0.f,0.f,0.f,0.f,0.f,0.f,0.f,0.f,0.f,0.f,0.f,0.f,0.f,0.f};
            const int arow = (32 * t + col) * 8;
#pragma unroll
            for (int kk = 0; kk < 4; ++kk) {
                const int sb = (2 * kk + hi) * 1024 + arow;
                bf16x8 a1 = *(const bf16x8*)&planeA[0 * 8192 + sb];
                bf16x8 a2 = *(const bf16x8*)&planeA[1 * 8192 + sb];
                bf16x8 a3 = *(const bf16x8*)&planeA[2 * 8192 + sb];
                acc0 = __builtin_amdgcn_mfma_f32_32x32x16_bf16(a1, Bv[0][kk], acc0, 0, 0, 0);
                acc1 = __builtin_amdgcn_mfma_f32_32x32x16_bf16(a1, Bv[1][kk], acc1, 0, 0, 0);
                acc0 = __builtin_amdgcn_mfma_f32_32x32x16_bf16(a2, Bv[0][kk], acc0, 0, 0, 0);
                acc1 = __builtin_amdgcn_mfma_f32_32x32x16_bf16(a2, Bv[1][kk], acc1, 0, 0, 0);
                acc0 = __builtin_amdgcn_mfma_f32_32x32x16_bf16(a1, Bv[2][kk], acc0, 0, 0, 0);
                acc1 = __builtin_amdgcn_mfma_f32_32x32x16_bf16(a3, Bv[0][kk], acc1, 0, 0, 0);
                acc0 = __builtin_amdgcn_mfma_f32_32x32x16_bf16(a2, Bv[2][kk], acc0, 0, 0, 0);
                acc1 = __builtin_amdgcn_mfma_f32_32x32x16_bf16(a3, Bv[1][kk], acc1, 0, 0, 0);
            }
            const int cbase = chunk * 128 + 32 * t + 4 * hi;
#pragma unroll
            for (int r = 0; r < 16; ++r) {
                const int row  = (r & 3) + 8 * (r >> 2);
                const int code = cbase + row;
                const float sc = (acc0[r] + acc1[r]) + se2[code];
                if (sc < best) { best = sc; bestk = code; }
            }
        }
    }

    float obest = __shfl_down(best, 32);
    int   oidx  = __shfl_down(bestk, 32);
    float ozz   = __shfl_down(zzp, 32);
    if (obest < best || (obest == best && oidx < bestk)) { best = obest; bestk = oidx; }
    const float zz = zzp + ozz;
    float contrib = (lane < 32) ? (best + zz) : 0.f;
    if (lane < 32) {
        sidx[wid * 32 + col] = bestk;
        atomicAdd(&hist[bestk], 1);
    }
#pragma unroll
    for (int off = 32; off > 0; off >>= 1) contrib += __shfl_down(contrib, off);
    if (lane == 0) swsum[wid] = contrib;
    __syncthreads();
    if (tid == 0) {
        float s = 0.f;
        for (int i = 0; i < 8; ++i) s += swsum[i];
        blockLoss[bid] = s;
    }

    if (lane < 32) {
        const int nn = bid * 256 + wid * 32 + col;
        enc[(size_t)nn * KCODES + bestk] = 1.0f;
    }

    {
        const int i  = tid & 255, c0 = (tid >> 8) * 32;
        const int k  = sidx[i];
        const int nn = bid * 256 + i, bb = nn >> 12, hh = nn & (HWSZ - 1);
        const float4* er = (const float4*)(emb + (size_t)k * DDIM + c0);
        float* ob = out + (size_t)bb * (DDIM * HWSZ) + hh;
#pragma unroll
        for (int m = 0; m < 8; ++m) {
            float4 q = er[m];
            ob[(size_t)(c0 + 4 * m    ) * HWSZ] = q.x;
            ob[(size_t)(c0 + 4 * m + 1) * HWSZ] = q.y;
            ob[(size_t)(c0 + 4 * m + 2) * HWSZ] = q.z;
            ob[(size_t)(c0 + 4 * m + 3) * HWSZ] = q.w;
        }
    }
}
// =================== end fallback ===================

__global__ __launch_bounds__(1024) void fin_kernel(const int* __restrict__ hist,
                                                   const float* __restrict__ blockLoss,
                                                   float* __restrict__ dout)
{
    __shared__ float redE[16];
    __shared__ float redL[16];
    const int t = threadIdx.x;

    float p = (float)hist[t] * (1.f / 131072.f);
    float term = p * logf(p + 1e-10f);
    float lv = (t < 512) ? blockLoss[t] : 0.f;
#pragma unroll
    for (int off = 32; off > 0; off >>= 1) {
        term += __shfl_down(term, off);
        lv   += __shfl_down(lv, off);
    }
    const int lane = t & 63, wid = t >> 6;
    if (lane == 0) { redE[wid] = term; redL[wid] = lv; }
    __syncthreads();
    if (t == 0) {
        float te = 0.f, tl = 0.f;
        for (int i = 0; i < 16; ++i) { te += redE[i]; tl += redL[i]; }
        dout[LOSS_OFF] = 0.25f * tl * (1.f / (131072.f * 64.f));
        dout[PERP_OFF] = expf(-te);
    }
}

extern "C" void kernel_launch(void* const* d_in, const int* in_sizes, int n_in,
                              void* d_out, int out_size, void* d_ws, size_t ws_size,
                              hipStream_t stream) {
    const float* z_e = (const float*)d_in[0];
    const float* emb = (const float*)d_in[1];
    float* out = (float*)d_out;
    float* enc = out + ENC_OFF;

    float* e2        = (float*)d_ws;
    int*   hist      = (int*)((char*)d_ws + 4096);
    float* blockLoss = (float*)((char*)d_ws + 8192);

    if (ws_size >= (size_t)WS_NEED) {
        unsigned short* planes = (unsigned short*)((char*)d_ws + PLANES_OFF);
        prep_kernel<<<4, 256, 0, stream>>>(emb, e2, hist, planes);
        vq_mfma2<<<NPTS / 256, 512, 0, stream>>>(z_e, (const bf16x8*)planes, e2, emb,
                                                 out, enc, hist, blockLoss);
    } else {
        e2_kernel<<<4, 256, 0, stream>>>(emb, e2, hist);
        vq_mfma<<<NPTS / 256, 512, 0, stream>>>(z_e, emb, e2, out, enc, hist, blockLoss);
    }
    fin_kernel<<<1, 1024, 0, stream>>>(hist, blockLoss, out);
}

// Round 5
// 296.834 us; speedup vs baseline: 3.1564x; 3.1564x over previous
//
#include <hip/hip_runtime.h>

typedef __attribute__((ext_vector_type(8)))  __bf16 bf16x8;
typedef __attribute__((ext_vector_type(16))) float  f32x16;

#define NPTS   131072          // B*H*W = 32*64*64
#define KCODES 1024
#define DDIM   64
#define HWSZ   4096

// d_out layout (floats): out[8388608] | loss | perplexity | encodings[131072*1024]
#define LOSS_OFF    8388608
#define PERP_OFF    8388609
#define ENC_OFF     8388610

// d_ws layout (bytes): [0,4096) e2 f32[1024] | [4096,8192) hist i32[1024] | [8192,10240) blockLoss f32[512]

__device__ __forceinline__ unsigned rnhi(float x) {
    // round-to-nearest-even bf16, returned as fp32 bit pattern (low 16 bits zero)
    unsigned u = __float_as_uint(x);
    return (u + 0x7fffu + ((u >> 16) & 1u)) & 0xffff0000u;
}

__device__ __forceinline__ void split3(float x, unsigned short& h1, unsigned short& h2, unsigned short& h3) {
    unsigned a = rnhi(x); float r1 = x - __uint_as_float(a);
    unsigned b = rnhi(r1); float r2 = r1 - __uint_as_float(b);
    unsigned c = rnhi(r2);
    h1 = (unsigned short)(a >> 16);
    h2 = (unsigned short)(b >> 16);
    h3 = (unsigned short)(c >> 16);
}

__global__ __launch_bounds__(256) void e2_kernel(const float* __restrict__ emb,
                                                 float* __restrict__ e2,
                                                 int* __restrict__ hist) {
    int k = blockIdx.x * 256 + threadIdx.x;
    hist[k] = 0;                       // zero histogram (1024 threads exactly)
    const float4* r = (const float4*)(emb + (size_t)k * DDIM);
    float s0 = 0.f, s1 = 0.f, s2 = 0.f, s3 = 0.f;
#pragma unroll
    for (int i = 0; i < 16; ++i) {
        float4 v = r[i];
        s0 = fmaf(v.x, v.x, s0);
        s1 = fmaf(v.y, v.y, s1);
        s2 = fmaf(v.z, v.z, s2);
        s3 = fmaf(v.w, v.w, s3);
    }
    e2[k] = (s0 + s1) + (s2 + s3);
}

// ---- compute: distances via MFMA, argmin, loss/hist, out-write, bestk marker ----
__global__ __launch_bounds__(512, 2) void vq_compute(
    const float* __restrict__ z_e, const float* __restrict__ emb,
    const float* __restrict__ e2g, float* __restrict__ out,
    float* __restrict__ enc, int* __restrict__ hist,
    float* __restrict__ blockLoss)
{
    // E-chunk planes: 3 splits x 8 k-slots x (128 codes x 8 dims) bf16
    __shared__ unsigned short planeA[3 * 8 * 1024];
    __shared__ float se2[KCODES];
    __shared__ int   sidx[256];
    __shared__ float swsum[8];

    const int tid  = threadIdx.x, bid = blockIdx.x;
    const int lane = tid & 63,    wid = tid >> 6;
    const int hi   = lane >> 5,   col = lane & 31;

    for (int i = tid; i < KCODES; i += 512) se2[i] = e2g[i];

    // ---- build B fragments: this wave's 32 points, 3-way bf16 split of z ----
    const int n  = bid * 256 + wid * 32 + col;
    const int b  = n >> 12, hw = n & (HWSZ - 1);
    const float* zp = z_e + (size_t)b * (DDIM * HWSZ) + hw;

    bf16x8 Bv[3][4];
    float zzp = 0.f;
#pragma unroll
    for (int kk = 0; kk < 4; ++kk) {
        union { unsigned u[4]; bf16x8 v; } p1, p2, p3;
#pragma unroll
        for (int m = 0; m < 4; ++m) {
            float x0 = zp[(size_t)(16 * kk + 8 * hi + 2 * m    ) * HWSZ];
            float x1 = zp[(size_t)(16 * kk + 8 * hi + 2 * m + 1) * HWSZ];
            zzp = fmaf(x0, x0, zzp);
            zzp = fmaf(x1, x1, zzp);
            unsigned short a0, b0, c0, a1, b1, c1;
            split3(x0, a0, b0, c0);
            split3(x1, a1, b1, c1);
            p1.u[m] = (unsigned)a0 | ((unsigned)a1 << 16);
            p2.u[m] = (unsigned)b0 | ((unsigned)b1 << 16);
            p3.u[m] = (unsigned)c0 | ((unsigned)c1 << 16);
        }
        Bv[0][kk] = p1.v; Bv[1][kk] = p2.v; Bv[2][kk] = p3.v;
    }

    float best = 3.4e38f;
    int   bestk = 0;

    for (int chunk = 0; chunk < 8; ++chunk) {
        __syncthreads();
        // ---- stage -2*E chunk (128 codes), 3-way split, [slot][code] layout ----
#pragma unroll
        for (int it = 0; it < 2; ++it) {
            const int code = tid & 127;
            const int sl   = (tid >> 7) + 4 * it;
            const float4* ep = (const float4*)(emb + (size_t)(chunk * 128 + code) * DDIM + sl * 8);
            float4 va = ep[0], vb = ep[1];
            float xs[8] = {va.x, va.y, va.z, va.w, vb.x, vb.y, vb.z, vb.w};
            unsigned w1[4], w2[4], w3[4];
#pragma unroll
            for (int m = 0; m < 4; ++m) {
                unsigned short a0, b0, c0, a1, b1, c1;
                split3(-2.f * xs[2 * m    ], a0, b0, c0);
                split3(-2.f * xs[2 * m + 1], a1, b1, c1);
                w1[m] = (unsigned)a0 | ((unsigned)a1 << 16);
                w2[m] = (unsigned)b0 | ((unsigned)b1 << 16);
                w3[m] = (unsigned)c0 | ((unsigned)c1 << 16);
            }
            const int off = sl * 1024 + code * 8;
            *(uint4*)&planeA[0 * 8192 + off] = make_uint4(w1[0], w1[1], w1[2], w1[3]);
            *(uint4*)&planeA[1 * 8192 + off] = make_uint4(w2[0], w2[1], w2[2], w2[3]);
            *(uint4*)&planeA[2 * 8192 + off] = make_uint4(w3[0], w3[1], w3[2], w3[3]);
        }
        __syncthreads();

        for (int t = 0; t < 4; ++t) {
            f32x16 acc0 = {0.f,0.f,0.f,0.f,0.f,0.f,0.f,0.f,0.f,0.f,0.f,0.f,0.f,0.f,0.f,0.f};
            f32x16 acc1 = {0.f,0.f,0.f,0.f,0.f,0.f,0.f,0.f,0.f,0.f,0.f,0.f,0.f,0.f,0.f,0.f};
            const int arow = (32 * t + col) * 8;
#pragma unroll
            for (int kk = 0; kk < 4; ++kk) {
                const int sb = (2 * kk + hi) * 1024 + arow;
                bf16x8 a1 = *(const bf16x8*)&planeA[0 * 8192 + sb];
                bf16x8 a2 = *(const bf16x8*)&planeA[1 * 8192 + sb];
                bf16x8 a3 = *(const bf16x8*)&planeA[2 * 8192 + sb];
                // 8 product terms (drop only (3,3)); two independent acc chains
                acc0 = __builtin_amdgcn_mfma_f32_32x32x16_bf16(a1, Bv[0][kk], acc0, 0, 0, 0);
                acc1 = __builtin_amdgcn_mfma_f32_32x32x16_bf16(a1, Bv[1][kk], acc1, 0, 0, 0);
                acc0 = __builtin_amdgcn_mfma_f32_32x32x16_bf16(a2, Bv[0][kk], acc0, 0, 0, 0);
                acc1 = __builtin_amdgcn_mfma_f32_32x32x16_bf16(a2, Bv[1][kk], acc1, 0, 0, 0);
                acc0 = __builtin_amdgcn_mfma_f32_32x32x16_bf16(a1, Bv[2][kk], acc0, 0, 0, 0);
                acc1 = __builtin_amdgcn_mfma_f32_32x32x16_bf16(a3, Bv[0][kk], acc1, 0, 0, 0);
                acc0 = __builtin_amdgcn_mfma_f32_32x32x16_bf16(a2, Bv[2][kk], acc0, 0, 0, 0);
                acc1 = __builtin_amdgcn_mfma_f32_32x32x16_bf16(a3, Bv[1][kk], acc1, 0, 0, 0);
            }
            const int cbase = chunk * 128 + 32 * t + 4 * hi;
#pragma unroll
            for (int r = 0; r < 16; ++r) {
                const int row  = (r & 3) + 8 * (r >> 2);   // verified C/D map (+4*hi folded into cbase)
                const int code = cbase + row;
                const float sc = (acc0[r] + acc1[r]) + se2[code];
                if (sc < best) { best = sc; bestk = code; }
            }
        }
    }

    // ---- merge lane pairs (col, col+32): other lane covers the other 16 rows ----
    float obest = __shfl_down(best, 32);
    int   oidx  = __shfl_down(bestk, 32);
    float ozz   = __shfl_down(zzp, 32);
    if (obest < best || (obest == best && oidx < bestk)) { best = obest; bestk = oidx; }
    const float zz = zzp + ozz;
    float contrib = (lane < 32) ? (best + zz) : 0.f;
    if (lane < 32) {
        sidx[wid * 32 + col] = bestk;
        atomicAdd(&hist[bestk], 1);
        // bestk marker at this point's enc-row start (enc_write reads then overwrites)
        ((int*)enc)[(size_t)n * KCODES] = bestk;
    }
#pragma unroll
    for (int off = 32; off > 0; off >>= 1) contrib += __shfl_down(contrib, off);
    if (lane == 0) swsum[wid] = contrib;
    __syncthreads();
    if (tid == 0) {
        float s = 0.f;
        for (int i = 0; i < 8; ++i) s += swsum[i];
        blockLoss[bid] = s;
    }

    // ---- quantized output: 2 threads/point, coalesced per channel ----
    {
        const int i  = tid & 255, c0 = (tid >> 8) * 32;
        const int k  = sidx[i];
        const int nn = bid * 256 + i, bb = nn >> 12, hh = nn & (HWSZ - 1);
        const float4* er = (const float4*)(emb + (size_t)k * DDIM + c0);
        float* ob = out + (size_t)bb * (DDIM * HWSZ) + hh;
#pragma unroll
        for (int m = 0; m < 8; ++m) {
            float4 q = er[m];
            ob[(size_t)(c0 + 4 * m    ) * HWSZ] = q.x;
            ob[(size_t)(c0 + 4 * m + 1) * HWSZ] = q.y;
            ob[(size_t)(c0 + 4 * m + 2) * HWSZ] = q.z;
            ob[(size_t)(c0 + 4 * m + 3) * HWSZ] = q.w;
        }
    }
}

// ---- streaming one-hot writer: 64 full rows per block, fill-shaped stores ----
__global__ __launch_bounds__(256) void enc_write(float* __restrict__ enc) {
    __shared__ int rk[64];
    const int t = threadIdx.x;
    const int row0 = blockIdx.x * 64;

    if (t < 64) rk[t] = ((const int*)enc)[(size_t)(row0 + t) * KCODES];
    __syncthreads();

    // enc byte base ≡ 8 mod 16, row stride 4096B -> rowp+2 floats is 16B-aligned
    for (int r = 0; r < 64; ++r) {
        const int k = rk[r];
        float* rowp = enc + (size_t)(row0 + r) * KCODES;
        if (t < 255) {
            const int j = 2 + 4 * t;
            float4 v;
            v.x = (k == j    ) ? 1.f : 0.f;
            v.y = (k == j + 1) ? 1.f : 0.f;
            v.z = (k == j + 2) ? 1.f : 0.f;
            v.w = (k == j + 3) ? 1.f : 0.f;
            *(float4*)(rowp + j) = v;
        } else {
            float2 h;
            h.x = (k == 0) ? 1.f : 0.f;
            h.y = (k == 1) ? 1.f : 0.f;
            *(float2*)rowp = h;
            float2 tl;
            tl.x = (k == 1022) ? 1.f : 0.f;
            tl.y = (k == 1023) ? 1.f : 0.f;
            *(float2*)(rowp + 1022) = tl;
        }
    }
}

__global__ __launch_bounds__(1024) void fin_kernel(const int* __restrict__ hist,
                                                   const float* __restrict__ blockLoss,
                                                   float* __restrict__ dout)
{
    __shared__ float redE[16];
    __shared__ float redL[16];
    const int t = threadIdx.x;

    float p = (float)hist[t] * (1.f / 131072.f);
    float term = p * logf(p + 1e-10f);
    float lv = (t < 512) ? blockLoss[t] : 0.f;
#pragma unroll
    for (int off = 32; off > 0; off >>= 1) {
        term += __shfl_down(term, off);
        lv   += __shfl_down(lv, off);
    }
    const int lane = t & 63, wid = t >> 6;
    if (lane == 0) { redE[wid] = term; redL[wid] = lv; }
    __syncthreads();
    if (t == 0) {
        float te = 0.f, tl = 0.f;
        for (int i = 0; i < 16; ++i) { te += redE[i]; tl += redL[i]; }
        dout[LOSS_OFF] = 0.25f * tl * (1.f / (131072.f * 64.f));
        dout[PERP_OFF] = expf(-te);
    }
}

extern "C" void kernel_launch(void* const* d_in, const int* in_sizes, int n_in,
                              void* d_out, int out_size, void* d_ws, size_t ws_size,
                              hipStream_t stream) {
    const float* z_e = (const float*)d_in[0];
    const float* emb = (const float*)d_in[1];
    float* out = (float*)d_out;
    float* enc = out + ENC_OFF;

    float* e2        = (float*)d_ws;
    int*   hist      = (int*)((char*)d_ws + 4096);
    float* blockLoss = (float*)((char*)d_ws + 8192);

    e2_kernel<<<4, 256, 0, stream>>>(emb, e2, hist);
    vq_compute<<<NPTS / 256, 512, 0, stream>>>(z_e, emb, e2, out, enc, hist, blockLoss);
    enc_write<<<NPTS / 64, 256, 0, stream>>>(enc);
    fin_kernel<<<1, 1024, 0, stream>>>(hist, blockLoss, out);
}

// Round 7
// 163.256 us; speedup vs baseline: 5.7390x; 1.8182x over previous
//
#include <hip/hip_runtime.h>

typedef __attribute__((ext_vector_type(8)))  __bf16 bf16x8;
typedef __attribute__((ext_vector_type(16))) float  f32x16;

#define NPTS   131072          // B*H*W = 32*64*64
#define KCODES 1024
#define DDIM   64
#define HWSZ   4096

// d_out layout (floats): out[8388608] | loss | perplexity | encodings[131072*1024]
#define LOSS_OFF    8388608
#define PERP_OFF    8388609
#define ENC_OFF     8388610

// main-path d_ws layout (bytes):
//   [0, 409600)          planes: 16 chunk-images x 25600 B
//        image: 3 planes x 8 slots x 64 codes x 16B  (24576) + eplane 64 x 16B (1024)
//   [409600, 413696)     hist i32[1024]
//   [413696, 415744)     blockLoss f32[512]
#define IMG_BYTES   25600
#define HIST_OFF    409600
#define BLOSS_OFF   413696
#define WS_NEED     415744

#define GLOBAL_AS __attribute__((address_space(1)))
#define LDS_AS    __attribute__((address_space(3)))

__device__ __forceinline__ unsigned rnhi(float x) {
    // round-to-nearest-even bf16, returned as fp32 bit pattern (low 16 bits zero)
    unsigned u = __float_as_uint(x);
    return (u + 0x7fffu + ((u >> 16) & 1u)) & 0xffff0000u;
}

__device__ __forceinline__ void split3(float x, unsigned short& h1, unsigned short& h2, unsigned short& h3) {
    unsigned a = rnhi(x); float r1 = x - __uint_as_float(a);
    unsigned b = rnhi(r1); float r2 = r1 - __uint_as_float(b);
    unsigned c = rnhi(r2);
    h1 = (unsigned short)(a >> 16);
    h2 = (unsigned short)(b >> 16);
    h3 = (unsigned short)(c >> 16);
}

// ---- prep: hist zero + per-chunk plane images (split3 of -2*emb, e2 splits) ----
__global__ __launch_bounds__(256) void prep_kernel(const float* __restrict__ emb,
                                                   uint4* __restrict__ planes,
                                                   int* __restrict__ hist) {
    const int k = blockIdx.x * 256 + threadIdx.x;   // code 0..1023
    hist[k] = 0;
    float row[DDIM];
    const float4* r = (const float4*)(emb + (size_t)k * DDIM);
    float s0 = 0.f, s1 = 0.f, s2 = 0.f, s3 = 0.f;
#pragma unroll
    for (int i = 0; i < 16; ++i) {
        float4 v = r[i];
        row[4 * i + 0] = v.x; row[4 * i + 1] = v.y;
        row[4 * i + 2] = v.z; row[4 * i + 3] = v.w;
        s0 = fmaf(v.x, v.x, s0);
        s1 = fmaf(v.y, v.y, s1);
        s2 = fmaf(v.z, v.z, s2);
        s3 = fmaf(v.w, v.w, s3);
    }
    const float e2v = (s0 + s1) + (s2 + s3);

    const int c  = k >> 6, lc = k & 63;
    uint4* img = planes + (size_t)c * (IMG_BYTES / 16);
#pragma unroll
    for (int sl = 0; sl < 8; ++sl) {
        unsigned w1[4], w2[4], w3[4];
#pragma unroll
        for (int m = 0; m < 4; ++m) {
            unsigned short a0, b0, c0, a1, b1, c1;
            split3(-2.f * row[sl * 8 + 2 * m    ], a0, b0, c0);
            split3(-2.f * row[sl * 8 + 2 * m + 1], a1, b1, c1);
            w1[m] = (unsigned)a0 | ((unsigned)a1 << 16);
            w2[m] = (unsigned)b0 | ((unsigned)b1 << 16);
            w3[m] = (unsigned)c0 | ((unsigned)c1 << 16);
        }
        img[0 * 512 + sl * 64 + lc] = make_uint4(w1[0], w1[1], w1[2], w1[3]);
        img[1 * 512 + sl * 64 + lc] = make_uint4(w2[0], w2[1], w2[2], w2[3]);
        img[2 * 512 + sl * 64 + lc] = make_uint4(w3[0], w3[1], w3[2], w3[3]);
    }
    // eplane: e2 splits at k-positions 0..2 (paired with B_one = {1,1,1,0,...})
    {
        unsigned short s1e, s2e, s3e;
        split3(e2v, s1e, s2e, s3e);
        img[1536 + lc] = make_uint4((unsigned)s1e | ((unsigned)s2e << 16), (unsigned)s3e, 0u, 0u);
    }
}

// ---- main: dbuf global_load_lds staging, 25 MFMA/tile, drip-feed enc zeroing ----
__global__ __launch_bounds__(512, 4) void vq_fused(
    const float* __restrict__ z_e, const char* __restrict__ planesg,
    const float* __restrict__ emb, float* __restrict__ out,
    float* __restrict__ enc, int* __restrict__ hist,
    float* __restrict__ blockLoss)
{
    __shared__ __align__(16) char sbuf[2][IMG_BYTES];
    __shared__ int   sidx[256];
    __shared__ float swsum[8];

    const int tid  = threadIdx.x, bid = blockIdx.x;
    const int lane = tid & 63,    wid = tid >> 6;
    const int hi   = lane >> 5,   col = lane & 31;

    // stage chunk 0 immediately (async, zero VALU)
    {
#pragma unroll
        for (int i = 0; i < 4; ++i) {
            const int seg = wid + 8 * i;
            if (seg < 25) {
                const char* g = planesg + seg * 1024 + lane * 16;
                __builtin_amdgcn_global_load_lds((const GLOBAL_AS void*)g,
                                                 (LDS_AS void*)(&sbuf[0][0] + seg * 1024), 16, 0, 0);
            }
        }
    }

    float* encSlice = enc + (size_t)bid * 256 * KCODES;
    float4* encF4   = (float4*)(encSlice + 2);          // 16B-aligned interior

    // ---- build B fragments: this wave's 32 points, 3-way bf16 split of z ----
    const int n  = bid * 256 + wid * 32 + col;
    const int b  = n >> 12, hw = n & (HWSZ - 1);
    const float* zp = z_e + (size_t)b * (DDIM * HWSZ) + hw;

    bf16x8 Bv0[4], Bv1[4], Bv2[4];
    float zzp = 0.f;
#pragma unroll
    for (int kk = 0; kk < 4; ++kk) {
        union { unsigned u[4]; bf16x8 v; } p1, p2, p3;
#pragma unroll
        for (int m = 0; m < 4; ++m) {
            float x0 = zp[(size_t)(16 * kk + 8 * hi + 2 * m    ) * HWSZ];
            float x1 = zp[(size_t)(16 * kk + 8 * hi + 2 * m + 1) * HWSZ];
            zzp = fmaf(x0, x0, zzp);
            zzp = fmaf(x1, x1, zzp);
            unsigned short a0, b0, c0, a1, b1, c1;
            split3(x0, a0, b0, c0);
            split3(x1, a1, b1, c1);
            p1.u[m] = (unsigned)a0 | ((unsigned)a1 << 16);
            p2.u[m] = (unsigned)b0 | ((unsigned)b1 << 16);
            p3.u[m] = (unsigned)c0 | ((unsigned)c1 << 16);
        }
        Bv0[kk] = p1.v; Bv1[kk] = p2.v; Bv2[kk] = p3.v;
    }

    // B_one = 1.0 at k-positions 0..2 (hi=0 half only)
    bf16x8 Bone;
    {
        union { unsigned u[4]; bf16x8 v; } o;
        o.u[0] = hi ? 0u : 0x3F803F80u;
        o.u[1] = hi ? 0u : 0x00003F80u;
        o.u[2] = 0u; o.u[3] = 0u;
        Bone = o.v;
    }

    __syncthreads();   // chunk 0 staged (each wave's vmcnt drained at barrier)

    float best = 3.4e38f;
    int   bestk = 0;
    const float4 z4 = make_float4(0.f, 0.f, 0.f, 0.f);

    for (int c = 0; c < 16; ++c) {
        const int cur = c & 1;
        // issue stage of next chunk into the other buffer (safe: its last readers
        // finished before the previous end-of-iter barrier)
        if (c + 1 < 16) {
            const char* gimg = planesg + (size_t)(c + 1) * IMG_BYTES;
#pragma unroll
            for (int i = 0; i < 4; ++i) {
                const int seg = wid + 8 * i;
                if (seg < 25) {
                    __builtin_amdgcn_global_load_lds((const GLOBAL_AS void*)(gimg + seg * 1024 + lane * 16),
                                                     (LDS_AS void*)(&sbuf[1 - cur][0] + seg * 1024), 16, 0, 0);
                }
            }
        }
        // drip-feed: zero 1/16 of this block's enc slice (drains under MFMA)
        {
            const int base = c * 4096 + tid;
#pragma unroll
            for (int j = 0; j < 8; ++j) {
                const int idx = base + j * 512;
                if (idx < 65535) encF4[idx] = z4;
            }
            if (c == 0) {
                if (tid == 0) *(float2*)encSlice = make_float2(0.f, 0.f);
                if (tid == 1) *(float2*)(encSlice + 262142) = make_float2(0.f, 0.f);
            }
        }

        const char* img = &sbuf[cur][0];
#pragma unroll
        for (int t = 0; t < 2; ++t) {
            const int rowoff = (32 * t + col) * 16;
            f32x16 acc = {0.f,0.f,0.f,0.f,0.f,0.f,0.f,0.f,0.f,0.f,0.f,0.f,0.f,0.f,0.f,0.f};
            // fold ||e||^2 into the chain: acc = e2 (exact via 3 bf16 splits x 1.0)
            bf16x8 eA = *(const bf16x8*)(img + 24576 + rowoff);
            acc = __builtin_amdgcn_mfma_f32_32x32x16_bf16(eA, Bone, acc, 0, 0, 0);
#pragma unroll
            for (int kk = 0; kk < 4; ++kk) {
                const char* bse = img + (2 * kk + hi) * 1024 + rowoff;
                bf16x8 a1 = *(const bf16x8*)(bse);
                bf16x8 a2 = *(const bf16x8*)(bse + 8192);
                acc = __builtin_amdgcn_mfma_f32_32x32x16_bf16(a1, Bv0[kk], acc, 0, 0, 0);
                acc = __builtin_amdgcn_mfma_f32_32x32x16_bf16(a2, Bv0[kk], acc, 0, 0, 0);
                acc = __builtin_amdgcn_mfma_f32_32x32x16_bf16(a1, Bv1[kk], acc, 0, 0, 0);
                acc = __builtin_amdgcn_mfma_f32_32x32x16_bf16(a2, Bv1[kk], acc, 0, 0, 0);
                bf16x8 a3 = *(const bf16x8*)(bse + 16384);
                acc = __builtin_amdgcn_mfma_f32_32x32x16_bf16(a3, Bv0[kk], acc, 0, 0, 0);
                acc = __builtin_amdgcn_mfma_f32_32x32x16_bf16(a1, Bv2[kk], acc, 0, 0, 0);
            }
            const int cbase = c * 64 + 32 * t + 4 * hi;
#pragma unroll
            for (int r = 0; r < 16; ++r) {
                const int code = cbase + (r & 3) + 8 * (r >> 2);   // verified C/D map
                const float sc = acc[r];
                if (sc < best) { best = sc; bestk = code; }
            }
        }
        __syncthreads();   // stage(c+1) + this chunk's stores drained; buffers safe
    }

    // ---- merge lane pairs (col, col+32): other lane covers the other 16 rows ----
    float obest = __shfl_down(best, 32);
    int   oidx  = __shfl_down(bestk, 32);
    float ozz   = __shfl_down(zzp, 32);
    if (obest < best || (obest == best && oidx < bestk)) { best = obest; bestk = oidx; }
    const float zz = zzp + ozz;
    float contrib = (lane < 32) ? (best + zz) : 0.f;
    if (lane < 32) {
        sidx[wid * 32 + col] = bestk;
        atomicAdd(&hist[bestk], 1);
    }
#pragma unroll
    for (int off = 32; off > 0; off >>= 1) contrib += __shfl_down(contrib, off);
    if (lane == 0) swsum[wid] = contrib;
    __syncthreads();   // all enc zero-stores drained; sidx visible
    if (tid == 0) {
        float s = 0.f;
        for (int i = 0; i < 8; ++i) s += swsum[i];
        blockLoss[bid] = s;
    }

    // ---- scatter the 1.0s (zeros for this slice are complete & visible) ----
    if (lane < 32) {
        const int nn = bid * 256 + wid * 32 + col;
        enc[(size_t)nn * KCODES + bestk] = 1.0f;
    }

    // ---- quantized output: 2 threads/point, coalesced per channel ----
    {
        const int i  = tid & 255, c0 = (tid >> 8) * 32;
        const int k  = sidx[i];
        const int nn = bid * 256 + i, bb = nn >> 12, hh = nn & (HWSZ - 1);
        const float4* er = (const float4*)(emb + (size_t)k * DDIM + c0);
        float* ob = out + (size_t)bb * (DDIM * HWSZ) + hh;
#pragma unroll
        for (int m = 0; m < 8; ++m) {
            float4 q = er[m];
            ob[(size_t)(c0 + 4 * m    ) * HWSZ] = q.x;
            ob[(size_t)(c0 + 4 * m + 1) * HWSZ] = q.y;
            ob[(size_t)(c0 + 4 * m + 2) * HWSZ] = q.z;
            ob[(size_t)(c0 + 4 * m + 3) * HWSZ] = q.w;
        }
    }
}

// =================== fallback path (ws too small): round-3 kernels ===================
__global__ __launch_bounds__(256) void e2_kernel(const float* __restrict__ emb,
                                                 float* __restrict__ e2,
                                                 int* __restrict__ hist) {
    int k = blockIdx.x * 256 + threadIdx.x;
    hist[k] = 0;
    const float4* r = (const float4*)(emb + (size_t)k * DDIM);
    float s0 = 0.f, s1 = 0.f, s2 = 0.f, s3 = 0.f;
#pragma unroll
    for (int i = 0; i < 16; ++i) {
        float4 v = r[i];
        s0 = fmaf(v.x, v.x, s0);
        s1 = fmaf(v.y, v.y, s1);
        s2 = fmaf(v.z, v.z, s2);
        s3 = fmaf(v.w, v.w, s3);
    }
    e2[k] = (s0 + s1) + (s2 + s3);
}

__global__ __launch_bounds__(512, 4) void vq_mfma(
    const float* __restrict__ z_e, const float* __restrict__ emb,
    const float* __restrict__ e2g, float* __restrict__ out,
    float* __restrict__ enc, int* __restrict__ hist,
    float* __restrict__ blockLoss)
{
    __shared__ unsigned short planeA[3 * 8 * 1024];
    __shared__ float se2[KCODES];
    __shared__ int   sidx[256];
    __shared__ float swsum[8];

    const int tid  = threadIdx.x, bid = blockIdx.x;
    const int lane = tid & 63,    wid = tid >> 6;
    const int hi   = lane >> 5,   col = lane & 31;

    for (int i = tid; i < KCODES; i += 512) se2[i] = e2g[i];

    float* encSlice = enc + (size_t)bid * 256 * KCODES;
    float4* encF4   = (float4*)(encSlice + 2);

    const int n  = bid * 256 + wid * 32 + col;
    const int b  = n >> 12, hw = n & (HWSZ - 1);
    const float* zp = z_e + (size_t)b * (DDIM * HWSZ) + hw;

    bf16x8 Bv[3][4];
    float zzp = 0.f;
#pragma unroll
    for (int kk = 0; kk < 4; ++kk) {
        union { unsigned u[4]; bf16x8 v; } p1, p2, p3;
#pragma unroll
        for (int m = 0; m < 4; ++m) {
            float x0 = zp[(size_t)(16 * kk + 8 * hi + 2 * m    ) * HWSZ];
            float x1 = zp[(size_t)(16 * kk + 8 * hi + 2 * m + 1) * HWSZ];
            zzp = fmaf(x0, x0, zzp);
            zzp = fmaf(x1, x1, zzp);
            unsigned short a0, b0, c0, a1, b1, c1;
            split3(x0, a0, b0, c0);
            split3(x1, a1, b1, c1);
            p1.u[m] = (unsigned)a0 | ((unsigned)a1 << 16);
            p2.u[m] = (unsigned)b0 | ((unsigned)b1 << 16);
            p3.u[m] = (unsigned)c0 | ((unsigned)c1 << 16);
        }
        Bv[0][kk] = p1.v; Bv[1][kk] = p2.v; Bv[2][kk] = p3.v;
    }

    float best = 3.4e38f;
    int   bestk = 0;

    for (int chunk = 0; chunk < 8; ++chunk) {
        __syncthreads();
#pragma unroll
        for (int it = 0; it < 2; ++it) {
            const int code = tid & 127;
            const int sl   = (tid >> 7) + 4 * it;
            const float4* ep = (const float4*)(emb + (size_t)(chunk * 128 + code) * DDIM + sl * 8);
            float4 va = ep[0], vb = ep[1];
            float xs[8] = {va.x, va.y, va.z, va.w, vb.x, vb.y, vb.z, vb.w};
            unsigned w1[4], w2[4], w3[4];
#pragma unroll
            for (int m = 0; m < 4; ++m) {
                unsigned short a0, b0, c0, a1, b1, c1;
                split3(-2.f * xs[2 * m    ], a0, b0, c0);
                split3(-2.f * xs[2 * m + 1], a1, b1, c1);
                w1[m] = (unsigned)a0 | ((unsigned)a1 << 16);
                w2[m] = (unsigned)b0 | ((unsigned)b1 << 16);
                w3[m] = (unsigned)c0 | ((unsigned)c1 << 16);
            }
            const int off = sl * 1024 + code * 8;
            *(uint4*)&planeA[0 * 8192 + off] = make_uint4(w1[0], w1[1], w1[2], w1[3]);
            *(uint4*)&planeA[1 * 8192 + off] = make_uint4(w2[0], w2[1], w2[2], w2[3]);
            *(uint4*)&planeA[2 * 8192 + off] = make_uint4(w3[0], w3[1], w3[2], w3[3]);
        }
        __syncthreads();

        {
            const float4 z4 = make_float4(0.f, 0.f, 0.f, 0.f);
            const int base = chunk * 8192 + tid;
#pragma unroll
            for (int it = 0; it < 16; ++it) {
                const int idx = base + it * 512;
                if (idx < 65535) encF4[idx] = z4;
            }
            if (chunk == 0) {
                if (tid == 0) *(float2*)encSlice = make_float2(0.f, 0.f);
                if (tid == 1) *(float2*)(encSlice + 262142) = make_float2(0.f, 0.f);
            }
        }

        for (int t = 0; t < 4; ++t) {
            f32x16 acc0 = {0.f,0.f,0.f,0.f,0.f,0.f,0.f,0.f,0.f,0.f,0.f,0.f,0.f,0.f,0.f,0.f};
            f32x16 acc1 = {0.f,0.f,0.f,0.f,0.f,0.f,0.f,0.f,0.f,0.f,0.f,0.f,0.f,0.f,0.f,0.f};
            const int arow = (32 * t + col) * 8;
#pragma unroll
            for (int kk = 0; kk < 4; ++kk) {
                const int sb = (2 * kk + hi) * 1024 + arow;
                bf16x8 a1 = *(const bf16x8*)&planeA[0 * 8192 + sb];
                bf16x8 a2 = *(const bf16x8*)&planeA[1 * 8192 + sb];
                bf16x8 a3 = *(const bf16x8*)&planeA[2 * 8192 + sb];
                acc0 = __builtin_amdgcn_mfma_f32_32x32x16_bf16(a1, Bv[0][kk], acc0, 0, 0, 0);
                acc1 = __builtin_amdgcn_mfma_f32_32x32x16_bf16(a1, Bv[1][kk], acc1, 0, 0, 0);
                acc0 = __builtin_amdgcn_mfma_f32_32x32x16_bf16(a2, Bv[0][kk], acc0, 0, 0, 0);
                acc1 = __builtin_amdgcn_mfma_f32_32x32x16_bf16(a2, Bv[1][kk], acc1, 0, 0, 0);
                acc0 = __builtin_amdgcn_mfma_f32_32x32x16_bf16(a1, Bv[2][kk], acc0, 0, 0, 0);
                acc1 = __builtin_amdgcn_mfma_f32_32x32x16_bf16(a3, Bv[0][kk], acc1, 0, 0, 0);
                acc0 = __builtin_amdgcn_mfma_f32_32x32x16_bf16(a2, Bv[2][kk], acc0, 0, 0, 0);
                acc1 = __builtin_amdgcn_mfma_f32_32x32x16_bf16(a3, Bv[1][kk], acc1, 0, 0, 0);
            }
            const int cbase = chunk * 128 + 32 * t + 4 * hi;
#pragma unroll
            for (int r = 0; r < 16; ++r) {
                const int row  = (r & 3) + 8 * (r >> 2);
                const int code = cbase + row;
                const float sc = (acc0[r] + acc1[r]) + se2[code];
                if (sc < best) { best = sc; bestk = code; }
            }
        }
    }

    float obest = __shfl_down(best, 32);
    int   oidx  = __shfl_down(bestk, 32);
    float ozz   = __shfl_down(zzp, 32);
    if (obest < best || (obest == best && oidx < bestk)) { best = obest; bestk = oidx; }
    const float zz = zzp + ozz;
    float contrib = (lane < 32) ? (best + zz) : 0.f;
    if (lane < 32) {
        sidx[wid * 32 + col] = bestk;
        atomicAdd(&hist[bestk], 1);
    }
#pragma unroll
    for (int off = 32; off > 0; off >>= 1) contrib += __shfl_down(contrib, off);
    if (lane == 0) swsum[wid] = contrib;
    __syncthreads();
    if (tid == 0) {
        float s = 0.f;
        for (int i = 0; i < 8; ++i) s += swsum[i];
        blockLoss[bid] = s;
    }

    if (lane < 32) {
        const int nn = bid * 256 + wid * 32 + col;
        enc[(size_t)nn * KCODES + bestk] = 1.0f;
    }

    {
        const int i  = tid & 255, c0 = (tid >> 8) * 32;
        const int k  = sidx[i];
        const int nn = bid * 256 + i, bb = nn >> 12, hh = nn & (HWSZ - 1);
        const float4* er = (const float4*)(emb + (size_t)k * DDIM + c0);
        float* ob = out + (size_t)bb * (DDIM * HWSZ) + hh;
#pragma unroll
        for (int m = 0; m < 8; ++m) {
            float4 q = er[m];
            ob[(size_t)(c0 + 4 * m    ) * HWSZ] = q.x;
            ob[(size_t)(c0 + 4 * m + 1) * HWSZ] = q.y;
            ob[(size_t)(c0 + 4 * m + 2) * HWSZ] = q.z;
            ob[(size_t)(c0 + 4 * m + 3) * HWSZ] = q.w;
        }
    }
}
// =================== end fallback ===================

__global__ __launch_bounds__(1024) void fin_kernel(const int* __restrict__ hist,
                                                   const float* __restrict__ blockLoss,
                                                   float* __restrict__ dout)
{
    __shared__ float redE[16];
    __shared__ float redL[16];
    const int t = threadIdx.x;

    float p = (float)hist[t] * (1.f / 131072.f);
    float term = p * logf(p + 1e-10f);
    float lv = (t < 512) ? blockLoss[t] : 0.f;
#pragma unroll
    for (int off = 32; off > 0; off >>= 1) {
        term += __shfl_down(term, off);
        lv   += __shfl_down(lv, off);
    }
    const int lane = t & 63, wid = t >> 6;
    if (lane == 0) { redE[wid] = term; redL[wid] = lv; }
    __syncthreads();
    if (t == 0) {
        float te = 0.f, tl = 0.f;
        for (int i = 0; i < 16; ++i) { te += redE[i]; tl += redL[i]; }
        dout[LOSS_OFF] = 0.25f * tl * (1.f / (131072.f * 64.f));
        dout[PERP_OFF] = expf(-te);
    }
}

extern "C" void kernel_launch(void* const* d_in, const int* in_sizes, int n_in,
                              void* d_out, int out_size, void* d_ws, size_t ws_size,
                              hipStream_t stream) {
    const float* z_e = (const float*)d_in[0];
    const float* emb = (const float*)d_in[1];
    float* out = (float*)d_out;
    float* enc = out + ENC_OFF;

    if (ws_size >= (size_t)WS_NEED) {
        uint4* planes    = (uint4*)d_ws;
        int*   hist      = (int*)((char*)d_ws + HIST_OFF);
        float* blockLoss = (float*)((char*)d_ws + BLOSS_OFF);
        prep_kernel<<<4, 256, 0, stream>>>(emb, planes, hist);
        vq_fused<<<NPTS / 256, 512, 0, stream>>>(z_e, (const char*)d_ws, emb,
                                                 out, enc, hist, blockLoss);
        fin_kernel<<<1, 1024, 0, stream>>>(hist, blockLoss, out);
    } else {
        float* e2        = (float*)d_ws;
        int*   hist      = (int*)((char*)d_ws + 4096);
        float* blockLoss = (float*)((char*)d_ws + 8192);
        e2_kernel<<<4, 256, 0, stream>>>(emb, e2, hist);
        vq_mfma<<<NPTS / 256, 512, 0, stream>>>(z_e, emb, e2, out, enc, hist, blockLoss);
        fin_kernel<<<1, 1024, 0, stream>>>(hist, blockLoss, out);
    }
}